// Round 18
// baseline (186.425 us; speedup 1.0000x reference)
//
#include <hip/hip_runtime.h>
#include <stdint.h>

#define HEADS 8
#define DM 512
#define TT 12
#define WIN 3
#define NN 325
#define BB 4
#define HD 64
#define MROWS (BB*TT*NN)                  // 15600 rows for QKV gemm
#define NSLAB (BB*TT*HEADS)               // 384 head-slabs
#define NKT 11                            // 32-key tiles per slab (11*32=352)
static const size_t QKV_ELE = (size_t)MROWS * DM;           // 7,987,200 elems per tensor
static const size_t FRAG_SLAB = (size_t)NKT * 4 * 64 * 8;   // 22528 elems per slab frag tensor

typedef unsigned short u16;
typedef __attribute__((ext_vector_type(8))) short bf16x8;
typedef __attribute__((ext_vector_type(4))) float f32x4;

#define MFMA(a,b,c) __builtin_amdgcn_mfma_f32_16x16x32_bf16(a, b, c, 0, 0, 0)
#define LG2E 1.44269504f
#define C8F  (-11.5415603f)               // -8*log2(e)

static __device__ __forceinline__ float ex2(float x) {
  float r; asm("v_exp_f32 %0, %1" : "=v"(r) : "v"(x)); return r;
}

static __device__ __forceinline__ u16 f2bf(float f) {
  uint32_t u = __float_as_uint(f);
  u += 0x7fff + ((u >> 16) & 1);   // RNE
  return (u16)(u >> 16);
}
// pack two f32 -> one u32 of 2 bf16 (truncating), lo in low half
static __device__ __forceinline__ uint32_t pk2(float hi, float lo) {
  return __builtin_amdgcn_perm(__float_as_uint(hi), __float_as_uint(lo), 0x07060302);
}
static __device__ __forceinline__ float bf2f(u16 h) {
  return __uint_as_float((uint32_t)h << 16);
}

// global -> LDS async DMA, 16B per lane (lds dest is wave-uniform base + lane*16)
typedef const __attribute__((address_space(1))) unsigned int* gas1;
typedef __attribute__((address_space(3))) unsigned int* las3;
static __device__ __forceinline__ void gll16(const void* g, void* l) {
  __builtin_amdgcn_global_load_lds((gas1)g, (las3)l, 16, 0, 0);
}

// ---------------- prep: adj fold+pack [0,3168) + W pack [3168,3936) + x pack [3936,11736) ----------------
__global__ __launch_bounds__(256) void prep(
    const float* __restrict__ adj, const float* __restrict__ x,
    const float* __restrict__ Wq, const float* __restrict__ Wk,
    const float* __restrict__ Wv, const float* __restrict__ bq,
    const float* __restrict__ bk, const float* __restrict__ bv,
    float* __restrict__ adjp, u16* __restrict__ xb,
    u16* __restrict__ Wb, float* __restrict__ biasc) {
  if (blockIdx.x < 3168) {
    // adj -> fragment layout, pre-folded u = av*log2e + C8 (pad cols = C8 exactly)
    int blk = blockIdx.x;           // (slab*6 + qt)*11 + kt
    int kt = blk % 11;
    int rest = blk / 11;
    int qt = rest % 6;
    int slab = rest / 6;            // b*12 + ta
    const float* src = adj + (size_t)slab * NN * NN;
    float* dst = adjp + (size_t)blk * 2048;
    int t = threadIdx.x;
    int s = t >> 6, lane = t & 63;
    int qi = lane & 15, g = lane >> 4;
    int row = qt * 64 + s * 16 + qi; if (row > NN - 1) row = NN - 1;
    int c0 = kt * 32 + g * 8;
    const float* sp = src + (size_t)row * NN;
    float v[8];
#pragma unroll
    for (int e = 0; e < 8; ++e) {
      int c = c0 + e;
      v[e] = (c < NN) ? __builtin_fmaf(sp[c], LG2E, C8F) : C8F;
    }
    float4 w0 = {v[0], v[1], v[2], v[3]};
    float4 w1 = {v[4], v[5], v[6], v[7]};
    *(float4*)(dst + t * 8) = w0;
    *(float4*)(dst + t * 8 + 4) = w1;
  } else if (blockIdx.x < 3936) {
    int i = (blockIdx.x - 3168) * 256 + threadIdx.x;
    const int n4 = (3 * 512 * 512) / 4;   // 196608
    if (i < n4) {
      int j = i << 2;
      int which = j >> 18;
      int off4 = i & ((512 * 512 / 4) - 1);
      const float* src = which == 0 ? Wq : (which == 1 ? Wk : Wv);
      float4 v = ((const float4*)src)[off4];
      uint32_t a0 = (uint32_t)f2bf(v.x) | ((uint32_t)f2bf(v.y) << 16);
      uint32_t a1 = (uint32_t)f2bf(v.z) | ((uint32_t)f2bf(v.w) << 16);
      ((uint2*)Wb)[i] = make_uint2(a0, a1);
    }
    if (i < 1536 / 4) {
      int j = i << 2;
      int which = j >> 9;
      int off4 = i & 127;
      const float* src = which == 0 ? bq : (which == 1 ? bk : bv);
      ((float4*)biasc)[i] = ((const float4*)src)[off4];
    }
  } else {
    // x f32 -> bf16 (truncating pk2, matches previous inline conversion accuracy)
    int i = (blockIdx.x - 3936) * 256 + threadIdx.x;   // < QKV_ELE/4 = 1,996,800
    float4 v = ((const float4*)x)[i];
    ((uint2*)xb)[i] = make_uint2(pk2(v.y, v.x), pk2(v.w, v.z));
  }
}

// ---------------- fused QKV projection GEMM: A and B staged via global_load_lds ----------------
__global__ __launch_bounds__(256) void proj_gemm(
    const u16* __restrict__ xb,     // [M][512] bf16
    const u16* __restrict__ W,      // [1536][512] bf16
    const float* __restrict__ bias, // [1536]
    u16* __restrict__ qkv)          // 3 x [B][T][H][N][64] bf16
{
  __shared__ u16 sA[128 * 32];
  __shared__ u16 sB[128 * 32];
  int bid = blockIdx.x;
  int ord = (bid & 7) * 183 + (bid >> 3);
  const int m0 = (ord / 12) * 128;
  const int n0 = (ord % 12) * 128;
  const int tid = threadIdx.x;
  const int lane = tid & 63;
  const int wid = tid >> 6;
  const int wr = wid >> 1, wc = wid & 1;

  f32x4 acc[4][4] = {};

  const int srow = tid >> 2;          // 0..63
  const int scol = (tid & 3) * 8;     // 0,8,16,24

  for (int k0 = 0; k0 < 512; k0 += 32) {
    __syncthreads();                  // prior frag reads done before overwrite
#pragma unroll
    for (int i = 0; i < 2; ++i) {
      int gm = m0 + i * 64 + srow; if (gm >= MROWS) gm = MROWS - 1;
      gll16(xb + (size_t)gm * 512 + k0 + scol, &sA[(i * 64 + wid * 16) * 32]);
      gll16(W + (size_t)(n0 + i * 64 + srow) * 512 + k0 + scol, &sB[(i * 64 + wid * 16) * 32]);
    }
    __syncthreads();                  // barrier drains vmcnt: DMAs landed
    bf16x8 af[4], bfr[4];
#pragma unroll
    for (int mi = 0; mi < 4; ++mi)
      af[mi] = *(const bf16x8*)&sA[(wr * 64 + mi * 16 + (lane & 15)) * 32 + (lane >> 4) * 8];
#pragma unroll
    for (int ni = 0; ni < 4; ++ni)
      bfr[ni] = *(const bf16x8*)&sB[(wc * 64 + ni * 16 + (lane & 15)) * 32 + (lane >> 4) * 8];
#pragma unroll
    for (int mi = 0; mi < 4; ++mi)
#pragma unroll
      for (int ni = 0; ni < 4; ++ni)
        acc[mi][ni] = MFMA(af[mi], bfr[ni], acc[mi][ni]);
  }

  const int lr = (lane >> 4) * 4;
  const int lc = lane & 15;
#pragma unroll
  for (int mi = 0; mi < 4; ++mi) {
#pragma unroll
    for (int j = 0; j < 4; ++j) {
      int gm = m0 + wr * 64 + mi * 16 + lr + j;
      if (gm < MROWS) {
        int b = gm / (TT * NN);
        int rem = gm - b * (TT * NN);
        int t = rem / NN;
        int n = rem - t * NN;
#pragma unroll
        for (int ni = 0; ni < 4; ++ni) {
          int e = n0 + wc * 64 + ni * 16 + lc;
          float val = acc[mi][ni][j] + bias[e];
          int which = e >> 9;
          int h = (e >> 6) & 7;
          int d = e & 63;
          qkv[(size_t)which * QKV_ELE + ((((size_t)(b * TT + t) * HEADS + h) * NN + n) << 6) + d] = f2bf(val);
        }
      }
    }
  }
}

// ---------------- K/V row-major -> MFMA fragment layout (coalesced both sides) ----------------
__global__ __launch_bounds__(256) void kv_pack(const u16* __restrict__ qkv,
                                               u16* __restrict__ kf, u16* __restrict__ vf) {
  int slab = blockIdx.x;
  const u16* K = qkv + QKV_ELE + ((size_t)slab * NN << 6);
  const u16* V = qkv + 2 * QKV_ELE + ((size_t)slab * NN << 6);
  u16* kout = kf + (size_t)slab * FRAG_SLAB;
  u16* vout = vf + (size_t)slab * FRAG_SLAB;
  int t = threadIdx.x;
  int f = t >> 6;           // 0..3
  int lane = t & 63;
  int qi = lane & 15, g = lane >> 4;
  int krow_l = ((qi >> 2) << 3) + (qi & 3) + ((f >> 1) << 2);
  int kd = ((f & 1) << 5) + g * 8;
  for (int kt = 0; kt < NKT; ++kt) {
    int row = kt * 32 + krow_l;
    bf16x8 kv = {};
    if (row < NN) kv = *(const bf16x8*)(K + ((size_t)row << 6) + kd);
    *(bf16x8*)(kout + ((size_t)kt * 4 + f) * 512 + lane * 8) = kv;
    union { u16 e[8]; bf16x8 v; } vv;
#pragma unroll
    for (int e = 0; e < 8; ++e) {
      int vrow = kt * 32 + g * 8 + e;
      vv.e[e] = (vrow < NN) ? V[((size_t)vrow << 6) + f * 16 + qi] : (u16)0;
    }
    *(bf16x8*)(vout + ((size_t)kt * 4 + f) * 512 + lane * 8) = vv.v;
  }
}

// ---------------- MFMA attention v15: r14 schedule + ones-MFMA lsum + setprio ----------------
// (256,2) locked (192+ regs/wave, 64KB LDS dbuf — both axes saturated, r9/11/15/16).
// lsum via 5th accumulator: accl[s] = MFMA(P, ones, accl[s]) -> each lane's
// accl[s][j] = full row-sum for q-row 4g+j (B=ones => C[m][n] = sum_k P[m][k]).
// Deletes 32 VALU adds/tile + all epilogue shuffles. s_setprio(1) around compute
// (T5: helps desynced attn waves, m191).
__global__ __launch_bounds__(256, 2) void attn(
    const u16* __restrict__ q,      // [B][T][H][N][64] bf16
    const u16* __restrict__ kf,     // K fragments
    const u16* __restrict__ vf,     // V fragments
    const float* __restrict__ adjp, // adj fragments (pre-folded u)
    u16* __restrict__ hcat)         // [B][36][N][512] bf16
{
  // [wave][buf][K/V][frag][512 u16] = 64 KB
  __shared__ u16 kvlds[4][2][2][4][512];

  const int tid = threadIdx.x;
  const int wid = tid >> 6;
  const int lane = tid & 63;
  const int qi = lane & 15;
  const int g = lane >> 4;

  // XCD swizzle: nwg = 1728 = 8 * 216
  int ord = (blockIdx.x & 7) * 216 + (blockIdx.x >> 3);
  int slab = ord / 36;               // 0..47 = b*12 + ta
  int inner = ord - slab * 36;
  int b = slab / 12;
  int ta = slab - b * 12;            // t_adj
  int ti = inner / 12;
  int r2 = inner - ti * 12;
  int qt = r2 >> 1;
  int hg = r2 & 1;

  int tadd = ti == 0 ? 3 : (ti == 1 ? 2 : 1);           // t = ta + tadd (mod 12)
  int ckv  = ti == 0 ? 9 : (ti == 1 ? 7 : 6);           // t_kv = t + ckv (mod 12)
  float qsc = ti == 0 ? 0.125f : (ti == 1 ? 0.015625f : 0.001953125f);
  int t = ta + tadd; if (t >= 12) t -= 12;
  int t_kv = t + ckv; if (t_kv >= 12) t_kv -= 12;
  int h = hg * 4 + wid;
  int q0 = qt * 64;

  const float nqC8 = -qsc * C8F;     // qu = fma(qsc, u, nqC8) = qsc*av*log2e

  const u16* qbase = q + ((((size_t)(b * TT + t) * HEADS + h) * NN) << 6);
  int kvslab = (b * TT + t_kv) * HEADS + h;
  const u16* kfb = kf + (size_t)kvslab * FRAG_SLAB + lane * 8;   // per-lane global src
  const u16* vfb = vf + (size_t)kvslab * FRAG_SLAB + lane * 8;
  const float* apb = adjp + (size_t)(slab * 6 + qt) * (11 * 2048) + lane * 8;

  // Q fragments (B-operand)
  bf16x8 qf[4][2];
#pragma unroll
  for (int s = 0; s < 4; ++s) {
    int qr = q0 + s * 16 + qi; if (qr > NN - 1) qr = NN - 1;
    const u16* qp = qbase + ((size_t)qr << 6) + g * 8;
    qf[s][0] = *(const bf16x8*)qp;
    qf[s][1] = *(const bf16x8*)(qp + 32);
  }

  const f32x4 z4 = {0.f, 0.f, 0.f, 0.f};
  const short OB = (short)0x3F80;   // bf16 1.0
  const bf16x8 onesv = {OB, OB, OB, OB, OB, OB, OB, OB};

  f32x4 acc[4][4] = {};
  f32x4 accl[4] = {};                // row-sum accumulator (ones-MFMA)

  // ---- prologue: stage tile 0 (gll into buf0) + adj tile-0 register prefetch ----
#pragma unroll
  for (int f = 0; f < 4; ++f) {
    gll16(kfb + (size_t)f * 512, &kvlds[wid][0][0][f][0]);
    gll16(vfb + (size_t)f * 512, &kvlds[wid][0][1][f][0]);
  }
  float4 fa[4], fb4[4];
#pragma unroll
  for (int s = 0; s < 4; ++s) {
    fa[s]  = *(const float4*)(apb + s * 512);
    fb4[s] = *(const float4*)(apb + s * 512 + 4);
  }

  for (int kt = 0; kt < 11; ++kt) {
    int cur = kt & 1;
    // ---- issue tile kt+1: 8 gll + 8 adj register loads ----
    float4 fan[4], fbn[4];
    if (kt < 10) {
      const u16* kp = kfb + (size_t)(kt + 1) * 2048;
      const u16* vp = vfb + (size_t)(kt + 1) * 2048;
#pragma unroll
      for (int f = 0; f < 4; ++f) {
        gll16(kp + (size_t)f * 512, &kvlds[wid][cur ^ 1][0][f][0]);
        gll16(vp + (size_t)f * 512, &kvlds[wid][cur ^ 1][1][f][0]);
      }
      const float* ap = apb + (size_t)(kt + 1) * 2048;
#pragma unroll
      for (int s = 0; s < 4; ++s) {
        fan[s] = *(const float4*)(ap + s * 512);
        fbn[s] = *(const float4*)(ap + s * 512 + 4);
      }
      asm volatile("s_waitcnt vmcnt(16)" ::: "memory");
    } else {
      asm volatile("s_waitcnt vmcnt(0)" ::: "memory");
    }

    // ---- read this tile's K/V frags from LDS (lane-linear, conflict-free) ----
    bf16x8 kc[4], vc[4];
#pragma unroll
    for (int f = 0; f < 4; ++f) {
      kc[f] = *(const bf16x8*)&kvlds[wid][cur][0][f][lane * 8];
      vc[f] = *(const bf16x8*)&kvlds[wid][cur][1][f][lane * 8];
    }

    // ---- compute tile kt ----
    __builtin_amdgcn_s_setprio(1);
#pragma unroll
    for (int s = 0; s < 4; ++s) {
      f32x4 s0 = MFMA(kc[0], qf[s][0], z4);
      s0 = MFMA(kc[1], qf[s][1], s0);
      f32x4 s1 = MFMA(kc[2], qf[s][0], z4);
      s1 = MFMA(kc[3], qf[s][1], s1);
      float p[8];
      float u, qu;
      u = fa[s].x;  qu = __builtin_fmaf(qsc, u, nqC8); p[0] = ex2(__builtin_fmaf(s0[0], qu, u));
      u = fa[s].y;  qu = __builtin_fmaf(qsc, u, nqC8); p[1] = ex2(__builtin_fmaf(s0[1], qu, u));
      u = fa[s].z;  qu = __builtin_fmaf(qsc, u, nqC8); p[2] = ex2(__builtin_fmaf(s0[2], qu, u));
      u = fa[s].w;  qu = __builtin_fmaf(qsc, u, nqC8); p[3] = ex2(__builtin_fmaf(s0[3], qu, u));
      u = fb4[s].x; qu = __builtin_fmaf(qsc, u, nqC8); p[4] = ex2(__builtin_fmaf(s1[0], qu, u));
      u = fb4[s].y; qu = __builtin_fmaf(qsc, u, nqC8); p[5] = ex2(__builtin_fmaf(s1[1], qu, u));
      u = fb4[s].z; qu = __builtin_fmaf(qsc, u, nqC8); p[6] = ex2(__builtin_fmaf(s1[2], qu, u));
      u = fb4[s].w; qu = __builtin_fmaf(qsc, u, nqC8); p[7] = ex2(__builtin_fmaf(s1[3], qu, u));
      union { uint32_t u[4]; bf16x8 v; } pu;
      pu.u[0] = pk2(p[1], p[0]);
      pu.u[1] = pk2(p[3], p[2]);
      pu.u[2] = pk2(p[5], p[4]);
      pu.u[3] = pk2(p[7], p[6]);
      acc[s][0] = MFMA(pu.v, vc[0], acc[s][0]);
      acc[s][1] = MFMA(pu.v, vc[1], acc[s][1]);
      acc[s][2] = MFMA(pu.v, vc[2], acc[s][2]);
      acc[s][3] = MFMA(pu.v, vc[3], acc[s][3]);
      accl[s]   = MFMA(pu.v, onesv, accl[s]);     // row-sum: C[m][*] = sum_k P[m][k]
    }
    __builtin_amdgcn_s_setprio(0);
#pragma unroll
    for (int s = 0; s < 4; ++s) { fa[s] = fan[s]; fb4[s] = fbn[s]; }
  }

  // ---- epilogue: exact pad correction, normalize, store (no cross-lane reduce) ----
  // P for pad keys is bf16(2^C8); sum 27 of them in bf16-rounded form for exactness.
  const float padcorr = 27.0f * bf2f(f2bf(ex2(C8F)));
  size_t hb = ((size_t)(b * 36 + ti * TT + t) * NN) << 9;
#pragma unroll
  for (int s = 0; s < 4; ++s) {
#pragma unroll
    for (int j = 0; j < 4; ++j) {
      float li = 1.0f / (accl[s][j] - padcorr);
      int qrow = q0 + s * 16 + 4 * g + j;
      if (qrow < NN) {
        u16* op = hcat + hb + ((size_t)qrow << 9) + h * 64 + qi;
#pragma unroll
        for (int dt = 0; dt < 4; ++dt)
          op[dt * 16] = f2bf(acc[s][dt][j] * li);
      }
    }
  }
}

// ---------------- temporal mix + residual + LayerNorm, wave-parallel ----------------
__global__ __launch_bounds__(256, 4) void mix_ln(
    const u16* __restrict__ hcat,
    const float* __restrict__ Wd,   // [12][36]
    const float* __restrict__ bd,   // [12]
    const float* __restrict__ x,
    const float* __restrict__ gamma,
    const float* __restrict__ beta,
    float* __restrict__ out)
{
  __shared__ u16 sH[36 * 512];      // 36 KB
  __shared__ float sWd[12 * 36];
  int bn = blockIdx.x;
  int b = bn / NN, n = bn - b * NN;
  int tid = threadIdx.x;
  int lane = tid & 63, wid = tid >> 6;

  for (int i = tid; i < 12 * 36; i += 256) sWd[i] = Wd[i];
  for (int i = tid; i < 36 * 128; i += 256) {    // uint2 = 4 bf16 per op
    int w = i >> 7, d4 = i & 127;
    *(uint2*)&sH[(w << 9) + (d4 << 2)] =
        *(const uint2*)&hcat[(((size_t)(b * 36 + w) * NN + n) << 9) + (d4 << 2)];
  }
  __syncthreads();

  const int d0 = lane * 8;
  float4 g0 = *(const float4*)&gamma[d0];
  float4 g1 = *(const float4*)&gamma[d0 + 4];
  float4 be0 = *(const float4*)&beta[d0];
  float4 be1 = *(const float4*)&beta[d0 + 4];

  for (int t = wid; t < TT; t += 4) {
    float a[8] = {};
    const float* wrow = &sWd[t * 36];
#pragma unroll 4
    for (int w = 0; w < 36; ++w) {
      float wv = wrow[w];                          // LDS broadcast
      bf16x8 hv = *(const bf16x8*)&sH[(w << 9) + d0];
#pragma unroll
      for (int j = 0; j < 8; ++j) a[j] = __builtin_fmaf(bf2f((u16)hv[j]), wv, a[j]);
    }
    size_t xoff = ((size_t)(b * TT + t) * NN + n) << 9;
    float4 x0 = *(const float4*)&x[xoff + d0];
    float4 x1 = *(const float4*)&x[xoff + d0 + 4];
    float bdt = bd[t];
    float y[8];
    y[0] = a[0] + bdt + x0.x;  y[1] = a[1] + bdt + x0.y;
    y[2] = a[2] + bdt + x0.z;  y[3] = a[3] + bdt + x0.w;
    y[4] = a[4] + bdt + x1.x;  y[5] = a[5] + bdt + x1.y;
    y[6] = a[6] + bdt + x1.z;  y[7] = a[7] + bdt + x1.w;
    float s = 0.f, ss = 0.f;
#pragma unroll
    for (int j = 0; j < 8; ++j) { s += y[j]; ss = __builtin_fmaf(y[j], y[j], ss); }
#pragma unroll
    for (int off = 32; off > 0; off >>= 1) {
      s += __shfl_xor(s, off);
      ss += __shfl_xor(ss, off);
    }
    float mu = s * (1.0f / 512.0f);
    float var = ss * (1.0f / 512.0f) - mu * mu;
    float rstd = rsqrtf(var + 1e-5f);
    float4 o0, o1;
    o0.x = (y[0] - mu) * rstd * g0.x + be0.x;
    o0.y = (y[1] - mu) * rstd * g0.y + be0.y;
    o0.z = (y[2] - mu) * rstd * g0.z + be0.z;
    o0.w = (y[3] - mu) * rstd * g0.w + be0.w;
    o1.x = (y[4] - mu) * rstd * g1.x + be1.x;
    o1.y = (y[5] - mu) * rstd * g1.y + be1.y;
    o1.z = (y[6] - mu) * rstd * g1.z + be1.z;
    o1.w = (y[7] - mu) * rstd * g1.w + be1.w;
    *(float4*)&out[xoff + d0] = o0;
    *(float4*)&out[xoff + d0 + 4] = o1;
  }
}

extern "C" void kernel_launch(void* const* d_in, const int* in_sizes, int n_in,
                              void* d_out, int out_size, void* d_ws, size_t ws_size,
                              hipStream_t stream) {
  const float* x     = (const float*)d_in[0];
  const float* adj   = (const float*)d_in[1];
  // d_in[2] = s_adj: unused by the reference
  const float* Wq    = (const float*)d_in[3];
  const float* bq    = (const float*)d_in[4];
  const float* Wk    = (const float*)d_in[5];
  const float* bk    = (const float*)d_in[6];
  const float* Wv    = (const float*)d_in[7];
  const float* bv    = (const float*)d_in[8];
  const float* Wd    = (const float*)d_in[9];
  const float* bd    = (const float*)d_in[10];
  const float* gamma = (const float*)d_in[11];
  const float* beta  = (const float*)d_in[12];
  float* out = (float*)d_out;

  char* ws = (char*)d_ws;
  size_t off = 0;
  auto alloc = [&](size_t bytes) {
    void* p = ws + off;
    off += (bytes + 255) & ~(size_t)255;
    return p;
  };
  u16* Wb     = (u16*)alloc(1536 * 512 * 2);               // [Wq;Wk;Wv] bf16
  float* bias = (float*)alloc(1536 * 4);                   // [bq;bk;bv]
  u16* xb     = (u16*)alloc(QKV_ELE * 2);                  // x in bf16
  u16* qkv    = (u16*)alloc(3 * QKV_ELE * 2);              // q,k,v bf16 row-major
  u16* hcat   = (u16*)alloc(3 * QKV_ELE * 2);              // (B,36,N,512) bf16
  u16* kfb    = (u16*)alloc((size_t)NSLAB * FRAG_SLAB * 2);   // K fragments
  u16* vfb    = (u16*)alloc((size_t)NSLAB * FRAG_SLAB * 2);   // V fragments
  float* adjp = (float*)alloc((size_t)48 * 6 * 11 * 2048 * 4); // adj fragments (folded u)

  prep<<<dim3(3936 + 7800), dim3(256), 0, stream>>>(adj, x, Wq, Wk, Wv, bq, bk, bv,
                                                    adjp, xb, Wb, bias);
  proj_gemm<<<dim3(1464), dim3(256), 0, stream>>>(xb, Wb, bias, qkv);
  kv_pack<<<dim3(NSLAB), dim3(256), 0, stream>>>(qkv, kfb, vfb);
  attn<<<dim3(BB * TT * WIN * 6 * 2), dim3(256), 0, stream>>>(qkv, kfb, vfb, adjp, hcat);
  mix_ln<<<dim3(BB * NN), dim3(256), 0, stream>>>(hcat, Wd, bd, x, gamma, beta, out);
}

// Round 19
// 184.684 us; speedup vs baseline: 1.0094x; 1.0094x over previous
//
#include <hip/hip_runtime.h>
#include <stdint.h>

#define HEADS 8
#define DM 512
#define TT 12
#define WIN 3
#define NN 325
#define BB 4
#define HD 64
#define MROWS (BB*TT*NN)                  // 15600 rows for QKV gemm
#define NSLAB (BB*TT*HEADS)               // 384 head-slabs
#define NKT 11                            // 32-key tiles per slab (11*32=352)
static const size_t QKV_ELE = (size_t)MROWS * DM;           // 7,987,200 elems per tensor
static const size_t FRAG_SLAB = (size_t)NKT * 4 * 64 * 8;   // 22528 elems per slab frag tensor

typedef unsigned short u16;
typedef __attribute__((ext_vector_type(8))) short bf16x8;
typedef __attribute__((ext_vector_type(4))) float f32x4;

#define MFMA(a,b,c) __builtin_amdgcn_mfma_f32_16x16x32_bf16(a, b, c, 0, 0, 0)
#define LG2E 1.44269504f
#define C8F  (-11.5415603f)               // -8*log2(e)

static __device__ __forceinline__ float ex2(float x) {
  float r; asm("v_exp_f32 %0, %1" : "=v"(r) : "v"(x)); return r;
}

static __device__ __forceinline__ u16 f2bf(float f) {
  uint32_t u = __float_as_uint(f);
  u += 0x7fff + ((u >> 16) & 1);   // RNE
  return (u16)(u >> 16);
}
// pack two f32 -> one u32 of 2 bf16 (truncating), lo in low half
static __device__ __forceinline__ uint32_t pk2(float hi, float lo) {
  return __builtin_amdgcn_perm(__float_as_uint(hi), __float_as_uint(lo), 0x07060302);
}
static __device__ __forceinline__ float bf2f(u16 h) {
  return __uint_as_float((uint32_t)h << 16);
}

// global -> LDS async DMA, 16B per lane (lds dest is wave-uniform base + lane*16)
typedef const __attribute__((address_space(1))) unsigned int* gas1;
typedef __attribute__((address_space(3))) unsigned int* las3;
static __device__ __forceinline__ void gll16(const void* g, void* l) {
  __builtin_amdgcn_global_load_lds((gas1)g, (las3)l, 16, 0, 0);
}

// ---------------- prep: adj fold+pack [0,3168) + W pack [3168,3936) + x pack [3936,11736) ----------------
__global__ __launch_bounds__(256) void prep(
    const float* __restrict__ adj, const float* __restrict__ x,
    const float* __restrict__ Wq, const float* __restrict__ Wk,
    const float* __restrict__ Wv, const float* __restrict__ bq,
    const float* __restrict__ bk, const float* __restrict__ bv,
    float* __restrict__ adjp, u16* __restrict__ xb,
    u16* __restrict__ Wb, float* __restrict__ biasc) {
  if (blockIdx.x < 3168) {
    // adj -> fragment layout, pre-folded u = av*log2e + C8 (pad cols = C8 exactly)
    int blk = blockIdx.x;           // (slab*6 + qt)*11 + kt
    int kt = blk % 11;
    int rest = blk / 11;
    int qt = rest % 6;
    int slab = rest / 6;            // b*12 + ta
    const float* src = adj + (size_t)slab * NN * NN;
    float* dst = adjp + (size_t)blk * 2048;
    int t = threadIdx.x;
    int s = t >> 6, lane = t & 63;
    int qi = lane & 15, g = lane >> 4;
    int row = qt * 64 + s * 16 + qi; if (row > NN - 1) row = NN - 1;
    int c0 = kt * 32 + g * 8;
    const float* sp = src + (size_t)row * NN;
    float v[8];
#pragma unroll
    for (int e = 0; e < 8; ++e) {
      int c = c0 + e;
      v[e] = (c < NN) ? __builtin_fmaf(sp[c], LG2E, C8F) : C8F;
    }
    float4 w0 = {v[0], v[1], v[2], v[3]};
    float4 w1 = {v[4], v[5], v[6], v[7]};
    *(float4*)(dst + t * 8) = w0;
    *(float4*)(dst + t * 8 + 4) = w1;
  } else if (blockIdx.x < 3936) {
    int i = (blockIdx.x - 3168) * 256 + threadIdx.x;
    const int n4 = (3 * 512 * 512) / 4;   // 196608
    if (i < n4) {
      int j = i << 2;
      int which = j >> 18;
      int off4 = i & ((512 * 512 / 4) - 1);
      const float* src = which == 0 ? Wq : (which == 1 ? Wk : Wv);
      float4 v = ((const float4*)src)[off4];
      uint32_t a0 = (uint32_t)f2bf(v.x) | ((uint32_t)f2bf(v.y) << 16);
      uint32_t a1 = (uint32_t)f2bf(v.z) | ((uint32_t)f2bf(v.w) << 16);
      ((uint2*)Wb)[i] = make_uint2(a0, a1);
    }
    if (i < 1536 / 4) {
      int j = i << 2;
      int which = j >> 9;
      int off4 = i & 127;
      const float* src = which == 0 ? bq : (which == 1 ? bk : bv);
      ((float4*)biasc)[i] = ((const float4*)src)[off4];
    }
  } else {
    // x f32 -> bf16 (truncating pk2, matches previous inline conversion accuracy)
    int i = (blockIdx.x - 3936) * 256 + threadIdx.x;   // < QKV_ELE/4 = 1,996,800
    float4 v = ((const float4*)x)[i];
    ((uint2*)xb)[i] = make_uint2(pk2(v.y, v.x), pk2(v.w, v.z));
  }
}

// ---------------- fused QKV projection GEMM: A and B staged via global_load_lds ----------------
__global__ __launch_bounds__(256) void proj_gemm(
    const u16* __restrict__ xb,     // [M][512] bf16
    const u16* __restrict__ W,      // [1536][512] bf16
    const float* __restrict__ bias, // [1536]
    u16* __restrict__ qkv)          // 3 x [B][T][H][N][64] bf16
{
  __shared__ u16 sA[128 * 32];
  __shared__ u16 sB[128 * 32];
  int bid = blockIdx.x;
  int ord = (bid & 7) * 183 + (bid >> 3);
  const int m0 = (ord / 12) * 128;
  const int n0 = (ord % 12) * 128;
  const int tid = threadIdx.x;
  const int lane = tid & 63;
  const int wid = tid >> 6;
  const int wr = wid >> 1, wc = wid & 1;

  f32x4 acc[4][4] = {};

  const int srow = tid >> 2;          // 0..63
  const int scol = (tid & 3) * 8;     // 0,8,16,24

  for (int k0 = 0; k0 < 512; k0 += 32) {
    __syncthreads();                  // prior frag reads done before overwrite
#pragma unroll
    for (int i = 0; i < 2; ++i) {
      int gm = m0 + i * 64 + srow; if (gm >= MROWS) gm = MROWS - 1;
      gll16(xb + (size_t)gm * 512 + k0 + scol, &sA[(i * 64 + wid * 16) * 32]);
      gll16(W + (size_t)(n0 + i * 64 + srow) * 512 + k0 + scol, &sB[(i * 64 + wid * 16) * 32]);
    }
    __syncthreads();                  // barrier drains vmcnt: DMAs landed
    bf16x8 af[4], bfr[4];
#pragma unroll
    for (int mi = 0; mi < 4; ++mi)
      af[mi] = *(const bf16x8*)&sA[(wr * 64 + mi * 16 + (lane & 15)) * 32 + (lane >> 4) * 8];
#pragma unroll
    for (int ni = 0; ni < 4; ++ni)
      bfr[ni] = *(const bf16x8*)&sB[(wc * 64 + ni * 16 + (lane & 15)) * 32 + (lane >> 4) * 8];
#pragma unroll
    for (int mi = 0; mi < 4; ++mi)
#pragma unroll
      for (int ni = 0; ni < 4; ++ni)
        acc[mi][ni] = MFMA(af[mi], bfr[ni], acc[mi][ni]);
  }

  const int lr = (lane >> 4) * 4;
  const int lc = lane & 15;
#pragma unroll
  for (int mi = 0; mi < 4; ++mi) {
#pragma unroll
    for (int j = 0; j < 4; ++j) {
      int gm = m0 + wr * 64 + mi * 16 + lr + j;
      if (gm < MROWS) {
        int b = gm / (TT * NN);
        int rem = gm - b * (TT * NN);
        int t = rem / NN;
        int n = rem - t * NN;
#pragma unroll
        for (int ni = 0; ni < 4; ++ni) {
          int e = n0 + wc * 64 + ni * 16 + lc;
          float val = acc[mi][ni][j] + bias[e];
          int which = e >> 9;
          int h = (e >> 6) & 7;
          int d = e & 63;
          qkv[(size_t)which * QKV_ELE + ((((size_t)(b * TT + t) * HEADS + h) * NN + n) << 6) + d] = f2bf(val);
        }
      }
    }
  }
}

// ---------------- K/V row-major -> MFMA fragment layout (coalesced both sides) ----------------
__global__ __launch_bounds__(256) void kv_pack(const u16* __restrict__ qkv,
                                               u16* __restrict__ kf, u16* __restrict__ vf) {
  int slab = blockIdx.x;
  const u16* K = qkv + QKV_ELE + ((size_t)slab * NN << 6);
  const u16* V = qkv + 2 * QKV_ELE + ((size_t)slab * NN << 6);
  u16* kout = kf + (size_t)slab * FRAG_SLAB;
  u16* vout = vf + (size_t)slab * FRAG_SLAB;
  int t = threadIdx.x;
  int f = t >> 6;           // 0..3
  int lane = t & 63;
  int qi = lane & 15, g = lane >> 4;
  int krow_l = ((qi >> 2) << 3) + (qi & 3) + ((f >> 1) << 2);
  int kd = ((f & 1) << 5) + g * 8;
  for (int kt = 0; kt < NKT; ++kt) {
    int row = kt * 32 + krow_l;
    bf16x8 kv = {};
    if (row < NN) kv = *(const bf16x8*)(K + ((size_t)row << 6) + kd);
    *(bf16x8*)(kout + ((size_t)kt * 4 + f) * 512 + lane * 8) = kv;
    union { u16 e[8]; bf16x8 v; } vv;
#pragma unroll
    for (int e = 0; e < 8; ++e) {
      int vrow = kt * 32 + g * 8 + e;
      vv.e[e] = (vrow < NN) ? V[((size_t)vrow << 6) + f * 16 + qi] : (u16)0;
    }
    *(bf16x8*)(vout + ((size_t)kt * 4 + f) * 512 + lane * 8) = vv.v;
  }
}

// ---------------- MFMA attention (r14 best, final): dbuf DMA-LDS + folded adj, (256,2) ----------------
// Structural plateau, measured across r9/r11/r15/r16/r18: ~192 regs/wave (128 arch
// + 64 acc) caps 2 waves/SIMD; 64 KB LDS dbuf independently caps 2 blocks/CU; the
// ones-MFMA lsum and setprio variants regressed. Per iteration exactly 16 VMEM ops
// issued (8 gll + 8 adj); vmcnt(16) retires prior-iteration ops only.
__global__ __launch_bounds__(256, 2) void attn(
    const u16* __restrict__ q,      // [B][T][H][N][64] bf16
    const u16* __restrict__ kf,     // K fragments
    const u16* __restrict__ vf,     // V fragments
    const float* __restrict__ adjp, // adj fragments (pre-folded u)
    u16* __restrict__ hcat)         // [B][36][N][512] bf16
{
  // [wave][buf][K/V][frag][512 u16] = 64 KB
  __shared__ u16 kvlds[4][2][2][4][512];

  const int tid = threadIdx.x;
  const int wid = tid >> 6;
  const int lane = tid & 63;
  const int qi = lane & 15;
  const int g = lane >> 4;

  // XCD swizzle: nwg = 1728 = 8 * 216
  int ord = (blockIdx.x & 7) * 216 + (blockIdx.x >> 3);
  int slab = ord / 36;               // 0..47 = b*12 + ta
  int inner = ord - slab * 36;
  int b = slab / 12;
  int ta = slab - b * 12;            // t_adj
  int ti = inner / 12;
  int r2 = inner - ti * 12;
  int qt = r2 >> 1;
  int hg = r2 & 1;

  int tadd = ti == 0 ? 3 : (ti == 1 ? 2 : 1);           // t = ta + tadd (mod 12)
  int ckv  = ti == 0 ? 9 : (ti == 1 ? 7 : 6);           // t_kv = t + ckv (mod 12)
  float qsc = ti == 0 ? 0.125f : (ti == 1 ? 0.015625f : 0.001953125f);
  int t = ta + tadd; if (t >= 12) t -= 12;
  int t_kv = t + ckv; if (t_kv >= 12) t_kv -= 12;
  int h = hg * 4 + wid;
  int q0 = qt * 64;

  const float nqC8 = -qsc * C8F;     // qu = fma(qsc, u, nqC8) = qsc*av*log2e

  const u16* qbase = q + ((((size_t)(b * TT + t) * HEADS + h) * NN) << 6);
  int kvslab = (b * TT + t_kv) * HEADS + h;
  const u16* kfb = kf + (size_t)kvslab * FRAG_SLAB + lane * 8;   // per-lane global src
  const u16* vfb = vf + (size_t)kvslab * FRAG_SLAB + lane * 8;
  const float* apb = adjp + (size_t)(slab * 6 + qt) * (11 * 2048) + lane * 8;

  // Q fragments (B-operand)
  bf16x8 qf[4][2];
#pragma unroll
  for (int s = 0; s < 4; ++s) {
    int qr = q0 + s * 16 + qi; if (qr > NN - 1) qr = NN - 1;
    const u16* qp = qbase + ((size_t)qr << 6) + g * 8;
    qf[s][0] = *(const bf16x8*)qp;
    qf[s][1] = *(const bf16x8*)(qp + 32);
  }

  const f32x4 z4 = {0.f, 0.f, 0.f, 0.f};

  f32x4 acc[4][4] = {};
  float lsum[4] = {0.f, 0.f, 0.f, 0.f};

  // ---- prologue: stage tile 0 (gll into buf0) + adj tile-0 register prefetch ----
#pragma unroll
  for (int f = 0; f < 4; ++f) {
    gll16(kfb + (size_t)f * 512, &kvlds[wid][0][0][f][0]);
    gll16(vfb + (size_t)f * 512, &kvlds[wid][0][1][f][0]);
  }
  float4 fa[4], fb4[4];
#pragma unroll
  for (int s = 0; s < 4; ++s) {
    fa[s]  = *(const float4*)(apb + s * 512);
    fb4[s] = *(const float4*)(apb + s * 512 + 4);
  }

  for (int kt = 0; kt < 11; ++kt) {
    int cur = kt & 1;
    // ---- issue tile kt+1: 8 gll + 8 adj register loads ----
    float4 fan[4], fbn[4];
    if (kt < 10) {
      const u16* kp = kfb + (size_t)(kt + 1) * 2048;
      const u16* vp = vfb + (size_t)(kt + 1) * 2048;
#pragma unroll
      for (int f = 0; f < 4; ++f) {
        gll16(kp + (size_t)f * 512, &kvlds[wid][cur ^ 1][0][f][0]);
        gll16(vp + (size_t)f * 512, &kvlds[wid][cur ^ 1][1][f][0]);
      }
      const float* ap = apb + (size_t)(kt + 1) * 2048;
#pragma unroll
      for (int s = 0; s < 4; ++s) {
        fan[s] = *(const float4*)(ap + s * 512);
        fbn[s] = *(const float4*)(ap + s * 512 + 4);
      }
      asm volatile("s_waitcnt vmcnt(16)" ::: "memory");
    } else {
      asm volatile("s_waitcnt vmcnt(0)" ::: "memory");
    }

    // ---- read this tile's K/V frags from LDS (lane-linear, conflict-free) ----
    bf16x8 kc[4], vc[4];
#pragma unroll
    for (int f = 0; f < 4; ++f) {
      kc[f] = *(const bf16x8*)&kvlds[wid][cur][0][f][lane * 8];
      vc[f] = *(const bf16x8*)&kvlds[wid][cur][1][f][lane * 8];
    }

    // ---- compute tile kt ----
#pragma unroll
    for (int s = 0; s < 4; ++s) {
      f32x4 s0 = MFMA(kc[0], qf[s][0], z4);
      s0 = MFMA(kc[1], qf[s][1], s0);
      f32x4 s1 = MFMA(kc[2], qf[s][0], z4);
      s1 = MFMA(kc[3], qf[s][1], s1);
      float p[8];
      float u, qu;
      u = fa[s].x;  qu = __builtin_fmaf(qsc, u, nqC8); p[0] = ex2(__builtin_fmaf(s0[0], qu, u));
      u = fa[s].y;  qu = __builtin_fmaf(qsc, u, nqC8); p[1] = ex2(__builtin_fmaf(s0[1], qu, u));
      u = fa[s].z;  qu = __builtin_fmaf(qsc, u, nqC8); p[2] = ex2(__builtin_fmaf(s0[2], qu, u));
      u = fa[s].w;  qu = __builtin_fmaf(qsc, u, nqC8); p[3] = ex2(__builtin_fmaf(s0[3], qu, u));
      u = fb4[s].x; qu = __builtin_fmaf(qsc, u, nqC8); p[4] = ex2(__builtin_fmaf(s1[0], qu, u));
      u = fb4[s].y; qu = __builtin_fmaf(qsc, u, nqC8); p[5] = ex2(__builtin_fmaf(s1[1], qu, u));
      u = fb4[s].z; qu = __builtin_fmaf(qsc, u, nqC8); p[6] = ex2(__builtin_fmaf(s1[2], qu, u));
      u = fb4[s].w; qu = __builtin_fmaf(qsc, u, nqC8); p[7] = ex2(__builtin_fmaf(s1[3], qu, u));
      lsum[s] += ((p[0] + p[1]) + (p[2] + p[3])) + ((p[4] + p[5]) + (p[6] + p[7]));
      union { uint32_t u[4]; bf16x8 v; } pu;
      pu.u[0] = pk2(p[1], p[0]);
      pu.u[1] = pk2(p[3], p[2]);
      pu.u[2] = pk2(p[5], p[4]);
      pu.u[3] = pk2(p[7], p[6]);
      acc[s][0] = MFMA(pu.v, vc[0], acc[s][0]);
      acc[s][1] = MFMA(pu.v, vc[1], acc[s][1]);
      acc[s][2] = MFMA(pu.v, vc[2], acc[s][2]);
      acc[s][3] = MFMA(pu.v, vc[3], acc[s][3]);
    }
#pragma unroll
    for (int s = 0; s < 4; ++s) { fa[s] = fan[s]; fb4[s] = fbn[s]; }
  }

  // ---- epilogue: exact pad correction, normalize, store ----
  const float padcorr = 27.0f * ex2(C8F);   // 27 pad keys, each contributes exactly 2^C8
  size_t hb = ((size_t)(b * 36 + ti * TT + t) * NN) << 9;
#pragma unroll
  for (int s = 0; s < 4; ++s) {
    float v = lsum[s];
    v += __shfl_xor(v, 16);
    v += __shfl_xor(v, 32);
    v -= padcorr;
    float linv = 1.0f / v;
#pragma unroll
    for (int j = 0; j < 4; ++j) {
      float li = __shfl(linv, g * 4 + j);
      int qrow = q0 + s * 16 + 4 * g + j;
      if (qrow < NN) {
        u16* op = hcat + hb + ((size_t)qrow << 9) + h * 64 + qi;
#pragma unroll
        for (int dt = 0; dt < 4; ++dt)
          op[dt * 16] = f2bf(acc[s][dt][j] * li);
      }
    }
  }
}

// ---------------- temporal mix + residual + LayerNorm, wave-parallel ----------------
__global__ __launch_bounds__(256, 4) void mix_ln(
    const u16* __restrict__ hcat,
    const float* __restrict__ Wd,   // [12][36]
    const float* __restrict__ bd,   // [12]
    const float* __restrict__ x,
    const float* __restrict__ gamma,
    const float* __restrict__ beta,
    float* __restrict__ out)
{
  __shared__ u16 sH[36 * 512];      // 36 KB
  __shared__ float sWd[12 * 36];
  int bn = blockIdx.x;
  int b = bn / NN, n = bn - b * NN;
  int tid = threadIdx.x;
  int lane = tid & 63, wid = tid >> 6;

  for (int i = tid; i < 12 * 36; i += 256) sWd[i] = Wd[i];
  for (int i = tid; i < 36 * 128; i += 256) {    // uint2 = 4 bf16 per op
    int w = i >> 7, d4 = i & 127;
    *(uint2*)&sH[(w << 9) + (d4 << 2)] =
        *(const uint2*)&hcat[(((size_t)(b * 36 + w) * NN + n) << 9) + (d4 << 2)];
  }
  __syncthreads();

  const int d0 = lane * 8;
  float4 g0 = *(const float4*)&gamma[d0];
  float4 g1 = *(const float4*)&gamma[d0 + 4];
  float4 be0 = *(const float4*)&beta[d0];
  float4 be1 = *(const float4*)&beta[d0 + 4];

  for (int t = wid; t < TT; t += 4) {
    float a[8] = {};
    const float* wrow = &sWd[t * 36];
#pragma unroll 4
    for (int w = 0; w < 36; ++w) {
      float wv = wrow[w];                          // LDS broadcast
      bf16x8 hv = *(const bf16x8*)&sH[(w << 9) + d0];
#pragma unroll
      for (int j = 0; j < 8; ++j) a[j] = __builtin_fmaf(bf2f((u16)hv[j]), wv, a[j]);
    }
    size_t xoff = ((size_t)(b * TT + t) * NN + n) << 9;
    float4 x0 = *(const float4*)&x[xoff + d0];
    float4 x1 = *(const float4*)&x[xoff + d0 + 4];
    float bdt = bd[t];
    float y[8];
    y[0] = a[0] + bdt + x0.x;  y[1] = a[1] + bdt + x0.y;
    y[2] = a[2] + bdt + x0.z;  y[3] = a[3] + bdt + x0.w;
    y[4] = a[4] + bdt + x1.x;  y[5] = a[5] + bdt + x1.y;
    y[6] = a[6] + bdt + x1.z;  y[7] = a[7] + bdt + x1.w;
    float s = 0.f, ss = 0.f;
#pragma unroll
    for (int j = 0; j < 8; ++j) { s += y[j]; ss = __builtin_fmaf(y[j], y[j], ss); }
#pragma unroll
    for (int off = 32; off > 0; off >>= 1) {
      s += __shfl_xor(s, off);
      ss += __shfl_xor(ss, off);
    }
    float mu = s * (1.0f / 512.0f);
    float var = ss * (1.0f / 512.0f) - mu * mu;
    float rstd = rsqrtf(var + 1e-5f);
    float4 o0, o1;
    o0.x = (y[0] - mu) * rstd * g0.x + be0.x;
    o0.y = (y[1] - mu) * rstd * g0.y + be0.y;
    o0.z = (y[2] - mu) * rstd * g0.z + be0.z;
    o0.w = (y[3] - mu) * rstd * g0.w + be0.w;
    o1.x = (y[4] - mu) * rstd * g1.x + be1.x;
    o1.y = (y[5] - mu) * rstd * g1.y + be1.y;
    o1.z = (y[6] - mu) * rstd * g1.z + be1.z;
    o1.w = (y[7] - mu) * rstd * g1.w + be1.w;
    *(float4*)&out[xoff + d0] = o0;
    *(float4*)&out[xoff + d0 + 4] = o1;
  }
}

extern "C" void kernel_launch(void* const* d_in, const int* in_sizes, int n_in,
                              void* d_out, int out_size, void* d_ws, size_t ws_size,
                              hipStream_t stream) {
  const float* x     = (const float*)d_in[0];
  const float* adj   = (const float*)d_in[1];
  // d_in[2] = s_adj: unused by the reference
  const float* Wq    = (const float*)d_in[3];
  const float* bq    = (const float*)d_in[4];
  const float* Wk    = (const float*)d_in[5];
  const float* bk    = (const float*)d_in[6];
  const float* Wv    = (const float*)d_in[7];
  const float* bv    = (const float*)d_in[8];
  const float* Wd    = (const float*)d_in[9];
  const float* bd    = (const float*)d_in[10];
  const float* gamma = (const float*)d_in[11];
  const float* beta  = (const float*)d_in[12];
  float* out = (float*)d_out;

  char* ws = (char*)d_ws;
  size_t off = 0;
  auto alloc = [&](size_t bytes) {
    void* p = ws + off;
    off += (bytes + 255) & ~(size_t)255;
    return p;
  };
  u16* Wb     = (u16*)alloc(1536 * 512 * 2);               // [Wq;Wk;Wv] bf16
  float* bias = (float*)alloc(1536 * 4);                   // [bq;bk;bv]
  u16* xb     = (u16*)alloc(QKV_ELE * 2);                  // x in bf16
  u16* qkv    = (u16*)alloc(3 * QKV_ELE * 2);              // q,k,v bf16 row-major
  u16* hcat   = (u16*)alloc(3 * QKV_ELE * 2);              // (B,36,N,512) bf16
  u16* kfb    = (u16*)alloc((size_t)NSLAB * FRAG_SLAB * 2);   // K fragments
  u16* vfb    = (u16*)alloc((size_t)NSLAB * FRAG_SLAB * 2);   // V fragments
  float* adjp = (float*)alloc((size_t)48 * 6 * 11 * 2048 * 4); // adj fragments (folded u)

  prep<<<dim3(3936 + 7800), dim3(256), 0, stream>>>(adj, x, Wq, Wk, Wv, bq, bk, bv,
                                                    adjp, xb, Wb, bias);
  proj_gemm<<<dim3(1464), dim3(256), 0, stream>>>(xb, Wb, bias, qkv);
  kv_pack<<<dim3(NSLAB), dim3(256), 0, stream>>>(qkv, kfb, vfb);
  attn<<<dim3(BB * TT * WIN * 6 * 2), dim3(256), 0, stream>>>(qkv, kfb, vfb, adjp, hcat);
  mix_ln<<<dim3(BB * NN), dim3(256), 0, stream>>>(hcat, Wd, bd, x, gamma, beta, out);
}